// Round 4
// baseline (339.283 us; speedup 1.0000x reference)
//
#include <hip/hip_runtime.h>
#include <hip/hip_fp16.h>
#include <cstdint>
#include <cstddef>

#define NEG_SLOPE 0.2f

// Edge packing relies on N <= 65536 (here N = 50000): edge = src | (dst<<16).
// Self-loops are NOT sorted: placed analytically (one per node, first slot).
// csrc[] stores the PACKED edge (src in low 16, dst in high 16).
// NOTE: bkt MUST NOT alias xl1 — scatter and gemm1 run concurrently (fused kernel).
#define NB 128        // nodes per bucket (391 finalize blocks -> fills CUs)
#define LOG_NB 7
#define MAXK 512

__device__ inline unsigned short f2bf(float f) {          // RNE fp32->bf16
    unsigned int u = __float_as_uint(f);
    u += 0x7FFFu + ((u >> 16) & 1u);
    return (unsigned short)(u >> 16);
}
__device__ inline float bf_lo(unsigned int u) { return __uint_as_float(u << 16); }
__device__ inline float bf_hi(unsigned int u) { return __uint_as_float(u & 0xFFFF0000u); }
__device__ inline float bfu(unsigned short u) { return __uint_as_float((unsigned int)u << 16); }
__device__ inline float lrelu(float t) { return t > 0.f ? t : NEG_SLOPE * t; }

// ---------------- P1: bucket histogram, 4-way wave-replicated (real edges only) ----------------
__global__ __launch_bounds__(256) void sort_count_kernel(const int* __restrict__ ei, int E,
                                                         int K, int CH, int* __restrict__ bcnt) {
    __shared__ int hist[4 * MAXK];
    int tid = threadIdx.x;
    int wiw = tid >> 6;
    for (int i = tid; i < K; i += 256) {
        hist[i] = 0; hist[MAXK + i] = 0; hist[2 * MAXK + i] = 0; hist[3 * MAXK + i] = 0;
    }
    __syncthreads();
    int lo = blockIdx.x * CH;
    int hi = lo + CH; if (hi > E) hi = E;
    for (int e = lo + tid; e < hi; e += 256)
        atomicAdd(&hist[wiw * MAXK + (ei[(size_t)E + e] >> LOG_NB)], 1);
    __syncthreads();
    for (int i = tid; i < K; i += 256) {
        int c = hist[i] + hist[MAXK + i] + hist[2 * MAXK + i] + hist[3 * MAXK + i];
        if (c) atomicAdd(&bcnt[i], c);
    }
}

// ---------------- P2: scan bucket counts ----------------
__global__ void sort_scan_kernel(const int* __restrict__ bcnt, int* __restrict__ boff,
                                 int* __restrict__ bcur, int K, int E) {
    __shared__ int buf[MAXK];
    int tid = threadIdx.x;   // 512 threads
    int v = (tid < K) ? bcnt[tid] : 0;
    buf[tid] = v;
    __syncthreads();
    for (int o = 1; o < MAXK; o <<= 1) {
        int t = (tid >= o) ? buf[tid - o] : 0;
        __syncthreads();
        buf[tid] += t;
        __syncthreads();
    }
    if (tid < K) {
        int ex = buf[tid] - v;
        boff[tid] = ex;
        bcur[tid] = ex;
    }
    if (tid == K) boff[K] = E;
}

// ---- GEMM + fused att dots body: K-tiles of 32 (low LDS, high occupancy) ----
// BF16IN: X is bf16 (packed ushort) instead of fp32.
// CHUNK_OUT: Ybf written feature-chunked [FOUT/32][N][32] (64 B rows for L2-affine gather).

template <int FOUT, int H, int ROWS, bool BF16IN, bool CHUNK_OUT>
__device__ __forceinline__ void gemm_att_body(const void* __restrict__ Xv,
                                              const float* __restrict__ W,
                                              const float* __restrict__ attS,
                                              const float* __restrict__ attD,
                                              unsigned short* __restrict__ Ybf,
                                              float* __restrict__ as_,
                                              float* __restrict__ ad_, int N, int bid,
                                              float* sX, float* sW) {
    constexpr int CG  = FOUT / 4;
    constexpr int RR  = (ROWS * FOUT) / 1024;   // rows per thread
    constexpr int LDX = 36;                     // 32 + 4 pad
    int tid = threadIdx.x;
    int rowbase = bid * ROWS;
    int cg = tid % CG;
    int rg = tid / CG;
    int r0 = rg * RR;

    float acc[RR][4];
#pragma unroll
    for (int i = 0; i < RR; i++)
#pragma unroll
        for (int c = 0; c < 4; c++) acc[i][c] = 0.f;

    for (int k0 = 0; k0 < 128; k0 += 32) {
        __syncthreads();
        for (int idx = tid; idx < ROWS * 8; idx += 256) {
            int r = idx >> 3, q = idx & 7;
            int row = rowbase + r;
            float4 val;
            if (row < N) {
                if constexpr (BF16IN) {
                    const unsigned short* Xb = (const unsigned short*)Xv;
                    ushort4 raw = *(const ushort4*)&Xb[(size_t)row * 128 + k0 + q * 4];
                    val = make_float4(bfu(raw.x), bfu(raw.y), bfu(raw.z), bfu(raw.w));
                } else {
                    const float* X = (const float*)Xv;
                    val = *(const float4*)&X[(size_t)row * 128 + k0 + q * 4];
                }
            } else {
                val = make_float4(0.f, 0.f, 0.f, 0.f);
            }
            *(float4*)&sX[r * LDX + q * 4] = val;
        }
        for (int idx = tid; idx < 8 * FOUT; idx += 256)
            *(float4*)&sW[idx * 4] = *(const float4*)&W[(size_t)k0 * FOUT + idx * 4];
        __syncthreads();
        for (int k = 0; k < 32; k += 4) {
            float4 xr[RR];
#pragma unroll
            for (int i = 0; i < RR; i++)
                xr[i] = *(const float4*)&sX[(r0 + i) * LDX + k];
#pragma unroll
            for (int kk = 0; kk < 4; kk++) {
                float4 wv = ((const float4*)(sW + (size_t)(k + kk) * FOUT))[cg];
#pragma unroll
                for (int i = 0; i < RR; i++) {
                    float xv = (&xr[i].x)[kk];
                    acc[i][0] = fmaf(xv, wv.x, acc[i][0]);
                    acc[i][1] = fmaf(xv, wv.y, acc[i][1]);
                    acc[i][2] = fmaf(xv, wv.z, acc[i][2]);
                    acc[i][3] = fmaf(xv, wv.w, acc[i][3]);
                }
            }
        }
    }

    // store bf16 Y
#pragma unroll
    for (int i = 0; i < RR; i++) {
        int row = rowbase + r0 + i;
        if (row < N) {
            ushort4 v;
            v.x = f2bf(acc[i][0]); v.y = f2bf(acc[i][1]);
            v.z = f2bf(acc[i][2]); v.w = f2bf(acc[i][3]);
            if constexpr (CHUNK_OUT) {
                int chunk = cg >> 3;          // (cg*4)/32
                int wc = (cg & 7) * 4;        // col within chunk
                *(ushort4*)(Ybf + ((size_t)chunk * N + row) * 32 + wc) = v;
            } else {
                *(ushort4*)(Ybf + (size_t)row * FOUT + cg * 4) = v;
            }
        }
    }

    // fused att dots
    float4 asv = ((const float4*)attS)[cg];
    float4 adv = ((const float4*)attD)[cg];
    int head = (H == 2) ? (cg >> 4) : 0;
#pragma unroll
    for (int i = 0; i < RR; i++) {
        float ps = acc[i][0] * asv.x + acc[i][1] * asv.y + acc[i][2] * asv.z + acc[i][3] * asv.w;
        float pd = acc[i][0] * adv.x + acc[i][1] * adv.y + acc[i][2] * adv.z + acc[i][3] * adv.w;
#pragma unroll
        for (int o = 1; o <= 8; o <<= 1) { ps += __shfl_xor(ps, o); pd += __shfl_xor(pd, o); }
        int row = rowbase + r0 + i;
        if ((tid & 15) == 0 && row < N) {
            as_[(size_t)row * H + head] = ps;
            ad_[(size_t)row * H + head] = pd;
        }
    }
}

// ---------------- P3 fused with layer-1 GEMM: blocks [0,G) scatter, rest gemm ----------------
__global__ __launch_bounds__(256) void scatter_gemm1_kernel(const int* __restrict__ ei, int E,
                                                            int K, int CH, int* __restrict__ bcur,
                                                            unsigned int* __restrict__ bkt,
                                                            const float* __restrict__ X,
                                                            const float* __restrict__ W1,
                                                            const float* __restrict__ attS,
                                                            const float* __restrict__ attD,
                                                            unsigned short* __restrict__ Ybf,
                                                            float* __restrict__ as_,
                                                            float* __restrict__ ad_, int N, int G) {
    __shared__ float sX[64 * 36];       // 9.2 KB
    __shared__ float sW[32 * 128];      // 16.4 KB
    if (blockIdx.x < G) {
        int* hist = (int*)sX;           // [4][MAXK] = 8 KB <= 9.2 KB
        int* base = (int*)sW;           // MAXK
        int* cur2 = (int*)sW + MAXK;    // MAXK
        int tid = threadIdx.x;
        int wiw = tid >> 6;
        for (int i = tid; i < K; i += 256) {
            hist[i] = 0; hist[MAXK + i] = 0; hist[2 * MAXK + i] = 0; hist[3 * MAXK + i] = 0;
        }
        __syncthreads();
        int lo = blockIdx.x * CH;
        int hi = lo + CH; if (hi > E) hi = E;
        for (int e = lo + tid; e < hi; e += 256)
            atomicAdd(&hist[wiw * MAXK + (ei[(size_t)E + e] >> LOG_NB)], 1);
        __syncthreads();
        for (int i = tid; i < K; i += 256) {
            int c = hist[i] + hist[MAXK + i] + hist[2 * MAXK + i] + hist[3 * MAXK + i];
            base[i] = c ? atomicAdd(&bcur[i], c) : 0;
            cur2[i] = 0;
        }
        __syncthreads();
        for (int e = lo + tid; e < hi; e += 256) {
            int s = ei[e];
            int d = ei[(size_t)E + e];
            int k = d >> LOG_NB;
            int r = atomicAdd(&cur2[k], 1);
            bkt[(size_t)base[k] + r] = (unsigned int)s | ((unsigned int)d << 16);
        }
    } else {
        gemm_att_body<128, 2, 64, false, true>(X, W1, attS, attD, Ybf, as_, ad_, N,
                                               blockIdx.x - G, sX, sW);
    }
}

// ---------------- standalone GEMM (layer 2): FOUT=64, bf16 input (h1), linear output ----------------
__global__ __launch_bounds__(256) void gemm2_kernel(const unsigned short* __restrict__ X,
                                                    const float* __restrict__ W,
                                                    const float* __restrict__ attS,
                                                    const float* __restrict__ attD,
                                                    unsigned short* __restrict__ Ybf,
                                                    float* __restrict__ as_,
                                                    float* __restrict__ ad_, int N) {
    __shared__ float sX[64 * 36];   // 9.2 KB
    __shared__ float sW[32 * 64];   // 8 KB
    gemm_att_body<64, 1, 64, true, false>(X, W, attS, attD, Ybf, as_, ad_, N, blockIdx.x, sX, sW);
}

// ---------------- P4: per-bucket CSR finalize (replicated hist; +1 self slot per node) ----------------
__global__ __launch_bounds__(256) void sort_finalize_kernel(const unsigned int* __restrict__ bkt,
                                                            const int* __restrict__ boff,
                                                            int* __restrict__ off,
                                                            unsigned int* __restrict__ csrc, int N) {
    __shared__ int nhist[4 * NB];
    __shared__ int part[256];
    __shared__ int loff[NB];
    int k = blockIdx.x;
    int tid = threadIdx.x;
    int wiw = tid >> 6;
    int node0 = k << LOG_NB;
    int nh = N - node0; if (nh > NB) nh = NB;
    int beg = boff[k], end = boff[k + 1];
    for (int i = tid; i < NB; i += 256) {
        nhist[i] = 0; nhist[NB + i] = 0; nhist[2 * NB + i] = 0; nhist[3 * NB + i] = 0;
    }
    __syncthreads();
    for (int e = beg + tid; e < end; e += 256)
        atomicAdd(&nhist[wiw * NB + ((bkt[e] >> 16) - node0)], 1);
    __syncthreads();
    int i0 = 2 * tid, i1 = 2 * tid + 1;
    int v0 = (i0 < nh) ? nhist[i0] + nhist[NB + i0] + nhist[2 * NB + i0] + nhist[3 * NB + i0] + 1 : 0;
    int v1 = (i1 < nh) ? nhist[i1] + nhist[NB + i1] + nhist[2 * NB + i1] + nhist[3 * NB + i1] + 1 : 0;
    part[tid] = v0 + v1;
    __syncthreads();
    for (int o = 1; o < 256; o <<= 1) {
        int t = (tid >= o) ? part[tid - o] : 0;
        __syncthreads();
        part[tid] += t;
        __syncthreads();
    }
    int gbase = beg + node0;   // node0 self slots precede this bucket
    int base = gbase + ((tid > 0) ? part[tid - 1] : 0);
    if (i0 < nh) loff[i0] = base;
    if (i1 < nh) loff[i1] = base + v0;
    __syncthreads();
    for (int i = tid; i < nh; i += 256) {
        int node = node0 + i;
        off[node] = loff[i];
        csrc[loff[i]] = (unsigned int)node | ((unsigned int)node << 16);  // self-loop first
        nhist[i] = loff[i] + 1;    // single-copy cursor
    }
    if (node0 + nh == N && tid == 0) off[N] = gbase + part[255];
    __syncthreads();
    for (int e = beg + tid; e < end; e += 256) {
        unsigned int p = bkt[e];
        int pos = atomicAdd(&nhist[(p >> 16) - node0], 1);
        csrc[pos] = p;   // keep packed (src | dst<<16)
    }
}

// ---------------- layer-1 alpha precompute: one wave per node, writes src|fp16(alpha) ----------------
// pae0/pae1 are head-major [EE] uint: low 16 = src id, high 16 = fp16 normalized alpha.

__global__ __launch_bounds__(256) void alpha1_kernel(const float* __restrict__ as_,
                                                     const float* __restrict__ ad_,
                                                     const int* __restrict__ off,
                                                     const unsigned int* __restrict__ csrc,
                                                     unsigned int* __restrict__ pae0,
                                                     unsigned int* __restrict__ pae1, int N) {
    int wiw  = threadIdx.x >> 6;
    int lane = threadIdx.x & 63;
    int node = blockIdx.x * 4 + wiw;
    if (node >= N) return;
    int beg = off[node], end = off[node + 1];
    int deg = end - beg;
    float2 adn = ((const float2*)ad_)[node];
    (void)wiw;

    if (deg <= 64) {
        int s = 0;
        float t0 = -1e30f, t1 = -1e30f;
        if (lane < deg) {
            s = (int)(csrc[beg + lane] & 0xFFFFu);
            float2 asv = ((const float2*)as_)[s];
            t0 = lrelu(asv.x + adn.x);
            t1 = lrelu(asv.y + adn.y);
        }
        float m0 = t0, m1 = t1;
#pragma unroll
        for (int o = 32; o; o >>= 1) {
            m0 = fmaxf(m0, __shfl_xor(m0, o));
            m1 = fmaxf(m1, __shfl_xor(m1, o));
        }
        float e0 = (lane < deg) ? __expf(t0 - m0) : 0.f;
        float e1 = (lane < deg) ? __expf(t1 - m1) : 0.f;
        float s0 = e0, s1 = e1;
#pragma unroll
        for (int o = 32; o; o >>= 1) { s0 += __shfl_xor(s0, o); s1 += __shfl_xor(s1, o); }
        if (lane < deg) {
            unsigned int h0 = (unsigned int)__half_as_ushort(__float2half(e0 / s0));
            unsigned int h1 = (unsigned int)__half_as_ushort(__float2half(e1 / s1));
            pae0[beg + lane] = (unsigned int)s | (h0 << 16);
            pae1[beg + lane] = (unsigned int)s | (h1 << 16);
        }
    } else {
        float m0 = -1e30f, m1 = -1e30f;
        for (int b = beg; b < end; b += 64) {
            int e = b + lane;
            if (e < end) {
                int s = (int)(csrc[e] & 0xFFFFu);
                float2 asv = ((const float2*)as_)[s];
                m0 = fmaxf(m0, lrelu(asv.x + adn.x));
                m1 = fmaxf(m1, lrelu(asv.y + adn.y));
            }
        }
#pragma unroll
        for (int o = 32; o; o >>= 1) {
            m0 = fmaxf(m0, __shfl_xor(m0, o));
            m1 = fmaxf(m1, __shfl_xor(m1, o));
        }
        float s0 = 0.f, s1 = 0.f;
        for (int b = beg; b < end; b += 64) {
            int e = b + lane;
            if (e < end) {
                int s = (int)(csrc[e] & 0xFFFFu);
                float2 asv = ((const float2*)as_)[s];
                s0 += __expf(lrelu(asv.x + adn.x) - m0);
                s1 += __expf(lrelu(asv.y + adn.y) - m1);
            }
        }
#pragma unroll
        for (int o = 32; o; o >>= 1) { s0 += __shfl_xor(s0, o); s1 += __shfl_xor(s1, o); }
        float i0 = 1.f / s0, i1 = 1.f / s1;
        for (int b = beg; b < end; b += 64) {
            int e = b + lane;
            if (e < end) {
                int s = (int)(csrc[e] & 0xFFFFu);
                float2 asv = ((const float2*)as_)[s];
                float a0 = __expf(lrelu(asv.x + adn.x) - m0) * i0;
                float a1 = __expf(lrelu(asv.y + adn.y) - m1) * i1;
                unsigned int h0 = (unsigned int)__half_as_ushort(__float2half(a0));
                unsigned int h1 = (unsigned int)__half_as_ushort(__float2half(a1));
                pae0[e] = (unsigned int)s | (h0 << 16);
                pae1[e] = (unsigned int)s | (h1 << 16);
            }
        }
    }
}

// ---------------- layer-1 chunked aggregate: XCD-affine feature chunks ----------------
// xlc: [4][N][32] bf16 (64 B rows). Block b -> chunk (b%8)&3, so each XCD's gather
// working set is N*64 B = 3.2 MB (< 4 MB L2). Per edge per chunk: one pae dword
// (src + fp16 alpha) + one 64 B row gather split over 4 lanes. No LDS, no softmax.

__global__ __launch_bounds__(256) void chunk_agg1_kernel(const unsigned short* __restrict__ xlc,
                                                         const unsigned int* __restrict__ pae0,
                                                         const unsigned int* __restrict__ pae1,
                                                         const float* __restrict__ bias,
                                                         const int* __restrict__ off,
                                                         unsigned short* __restrict__ out,
                                                         int N) {
    int bid   = blockIdx.x;
    int slot  = bid & 7;
    int chunk = slot & 3;
    int half  = slot >> 2;
    int blkin = (bid >> 3) * 2 + half;            // block index within chunk
    int wiw   = threadIdx.x >> 6;
    int lane  = threadIdx.x & 63;
    int node  = blkin * 4 + wiw;
    if (node >= N) return;

    int beg = off[node];
    int deg = off[node + 1] - beg;
    int le = lane >> 2;        // edge slot [0,16)
    int li = lane & 3;         // 16 B piece of the 64 B row

    const unsigned int* pae = (chunk & 2) ? pae1 : pae0;
    const char* xb = (const char*)xlc + ((size_t)chunk * N) * 64 + li * 16;

    float acc[8];
#pragma unroll
    for (int i = 0; i < 8; i++) acc[i] = 0.f;

    int rounds = (deg + 15) >> 4;
#pragma unroll 4
    for (int r = 0; r < rounds; r++) {
        int e = r * 16 + le;
        unsigned int p = (e < deg) ? pae[beg + e] : 0u;
        float a = __half2float(__ushort_as_half((unsigned short)(p >> 16)));
        int s = (int)(p & 0xFFFFu);
        uint4 v = *(const uint4*)(xb + ((size_t)s << 6));
        acc[0] = fmaf(a, bf_lo(v.x), acc[0]); acc[1] = fmaf(a, bf_hi(v.x), acc[1]);
        acc[2] = fmaf(a, bf_lo(v.y), acc[2]); acc[3] = fmaf(a, bf_hi(v.y), acc[3]);
        acc[4] = fmaf(a, bf_lo(v.z), acc[4]); acc[5] = fmaf(a, bf_hi(v.z), acc[5]);
        acc[6] = fmaf(a, bf_lo(v.w), acc[6]); acc[7] = fmaf(a, bf_hi(v.w), acc[7]);
    }
#pragma unroll
    for (int o = 4; o <= 32; o <<= 1)
#pragma unroll
        for (int i = 0; i < 8; i++) acc[i] += __shfl_xor(acc[i], o);

    if (lane < 4) {   // li = lane, le = 0
        const float* bp = bias + chunk * 32 + lane * 8;
        unsigned int w0 = (unsigned int)f2bf(fmaxf(acc[0] + bp[0], 0.f)) |
                          ((unsigned int)f2bf(fmaxf(acc[1] + bp[1], 0.f)) << 16);
        unsigned int w1 = (unsigned int)f2bf(fmaxf(acc[2] + bp[2], 0.f)) |
                          ((unsigned int)f2bf(fmaxf(acc[3] + bp[3], 0.f)) << 16);
        unsigned int w2 = (unsigned int)f2bf(fmaxf(acc[4] + bp[4], 0.f)) |
                          ((unsigned int)f2bf(fmaxf(acc[5] + bp[5], 0.f)) << 16);
        unsigned int w3 = (unsigned int)f2bf(fmaxf(acc[6] + bp[6], 0.f)) |
                          ((unsigned int)f2bf(fmaxf(acc[7] + bp[7], 0.f)) << 16);
        *(uint4*)(out + (size_t)node * 128 + chunk * 32 + lane * 8) = make_uint4(w0, w1, w2, w3);
    }
}

// ---------------- layer-2 softmax+aggregate: one wave per node, H=1, fp32 out ----------------
// (unchanged R0/R3 structure)

__global__ __launch_bounds__(256) void agg2_kernel(const unsigned short* __restrict__ xl,
                                                   const float* __restrict__ as_,
                                                   const float* __restrict__ ad_,
                                                   const float* __restrict__ bias,
                                                   const int* __restrict__ off,
                                                   const unsigned int* __restrict__ csrc,
                                                   float* __restrict__ out, int N) {
    __shared__ float2 sps[4][64];   // {p, as_int(byteoff)}
    int wiw  = threadIdx.x >> 6;
    int lane = threadIdx.x & 63;
    int node = blockIdx.x * 4 + wiw;
    if (node >= N) return;
    int beg = off[node], end = off[node + 1];
    int deg = end - beg;
    float adn = ad_[node];

    int cl  = lane & 7;
    int sub = lane >> 3;
    float acc[8];
#pragma unroll
    for (int i = 0; i < 8; i++) acc[i] = 0.f;
    const char* xbase = (const char*)xl + cl * 16;   // + src*128

    if (deg <= 64) {
        int so = 0;
        float t = -1e30f;
        if (lane < deg) {
            int s = (int)(csrc[beg + lane] & 0xFFFFu);
            so = s << 7;
            t = as_[s] + adn;
            t = t > 0.f ? t : NEG_SLOPE * t;
        }
        float m = t;
#pragma unroll
        for (int o = 32; o; o >>= 1) m = fmaxf(m, __shfl_xor(m, o));
        float evv = (lane < deg) ? __expf(t - m) : 0.f;
        float sum = evv;
#pragma unroll
        for (int o = 32; o; o >>= 1) sum += __shfl_xor(sum, o);
        sps[wiw][lane] = make_float2(evv / sum, __int_as_float(so));
        int iters = (deg + 7) >> 3;
#pragma unroll 8
        for (int j = 0; j < iters; j++) {
            float2 q = sps[wiw][j * 8 + sub];
            float a  = q.x;
            uint4 v  = *(const uint4*)(xbase + __float_as_int(q.y));
            acc[0] = fmaf(a, bf_lo(v.x), acc[0]); acc[1] = fmaf(a, bf_hi(v.x), acc[1]);
            acc[2] = fmaf(a, bf_lo(v.y), acc[2]); acc[3] = fmaf(a, bf_hi(v.y), acc[3]);
            acc[4] = fmaf(a, bf_lo(v.z), acc[4]); acc[5] = fmaf(a, bf_hi(v.z), acc[5]);
            acc[6] = fmaf(a, bf_lo(v.w), acc[6]); acc[7] = fmaf(a, bf_hi(v.w), acc[7]);
        }
    } else {
        float m = -1e30f;
        for (int b = beg; b < end; b += 64) {
            int e = b + lane;
            if (e < end) {
                float t = as_[csrc[e] & 0xFFFFu] + adn;
                t = t > 0.f ? t : NEG_SLOPE * t;
                m = fmaxf(m, t);
            }
        }
#pragma unroll
        for (int o = 32; o; o >>= 1) m = fmaxf(m, __shfl_xor(m, o));
        float sum = 0.f;
        for (int b = beg; b < end; b += 64) {
            int e = b + lane;
            if (e < end) {
                float t = as_[csrc[e] & 0xFFFFu] + adn;
                t = t > 0.f ? t : NEG_SLOPE * t;
                sum += __expf(t - m);
            }
        }
#pragma unroll
        for (int o = 32; o; o >>= 1) sum += __shfl_xor(sum, o);
        float inv = 1.f / sum;
        for (int b = beg; b < end; b += 64) {
            int cnt = end - b; if (cnt > 64) cnt = 64;
            float p = 0.f; int so = 0;
            if (lane < cnt) {
                int s = (int)(csrc[b + lane] & 0xFFFFu);
                so = s << 7;
                float t = as_[s] + adn;
                t = t > 0.f ? t : NEG_SLOPE * t;
                p = __expf(t - m) * inv;
            }
            sps[wiw][lane] = make_float2(p, __int_as_float(so));
            int iters = (cnt + 7) >> 3;
#pragma unroll 8
            for (int j = 0; j < iters; j++) {
                float2 q = sps[wiw][j * 8 + sub];
                float a  = q.x;
                uint4 v  = *(const uint4*)(xbase + __float_as_int(q.y));
                acc[0] = fmaf(a, bf_lo(v.x), acc[0]); acc[1] = fmaf(a, bf_hi(v.x), acc[1]);
                acc[2] = fmaf(a, bf_lo(v.y), acc[2]); acc[3] = fmaf(a, bf_hi(v.y), acc[3]);
                acc[4] = fmaf(a, bf_lo(v.z), acc[4]); acc[5] = fmaf(a, bf_hi(v.z), acc[5]);
                acc[6] = fmaf(a, bf_lo(v.w), acc[6]); acc[7] = fmaf(a, bf_hi(v.w), acc[7]);
            }
        }
    }
#pragma unroll
    for (int o = 8; o <= 32; o <<= 1)
#pragma unroll
        for (int i = 0; i < 8; i++) acc[i] += __shfl_xor(acc[i], o);
    if (sub == 0) {
        float* op = out + (size_t)node * 64 + cl * 8;
        const float* bp = bias + cl * 8;
#pragma unroll
        for (int i = 0; i < 8; i++) op[i] = fmaxf(acc[i] + bp[i], 0.f);
    }
}

// ---------------- launcher ----------------

extern "C" void kernel_launch(void* const* d_in, const int* in_sizes, int n_in,
                              void* d_out, int out_size, void* d_ws, size_t ws_size,
                              hipStream_t stream) {
    const float* x        = (const float*)d_in[0];
    const int*   ei       = (const int*)d_in[1];   // int32 per harness convention
    const float* W1       = (const float*)d_in[2];
    const float* attS1    = (const float*)d_in[3];
    const float* attD1    = (const float*)d_in[4];
    const float* b1       = (const float*)d_in[5];
    const float* W2       = (const float*)d_in[6];
    const float* attS2    = (const float*)d_in[7];
    const float* attD2    = (const float*)d_in[8];
    const float* b2       = (const float*)d_in[9];
    float* out            = (float*)d_out;

    int N  = in_sizes[0] / 128;
    int E  = in_sizes[1] / 2;
    int EE = E + N;                    // with self-loops
    int K  = (N + NB - 1) >> LOG_NB;   // buckets (391 for N=50000)

    char* w = (char*)d_ws;
    auto alloc = [&](size_t bytes) -> void* {
        void* p = (void*)w;
        w += (bytes + 255) & ~(size_t)255;
        return p;
    };
    int*   bcnt = (int*)alloc((size_t)(K + 1) * 4);
    int*   boff = (int*)alloc((size_t)(K + 1) * 4);
    int*   bcur = (int*)alloc((size_t)(K + 1) * 4);
    int*   off  = (int*)alloc((size_t)(N + 1) * 4);
    unsigned int* csrc = (unsigned int*)alloc((size_t)EE * 4);
    unsigned int* bkt  = (unsigned int*)alloc((size_t)E * 4);           // OWN buffer (no alias!)
    unsigned short* xl1 = (unsigned short*)alloc((size_t)N * 128 * 2);  // bf16, CHUNKED [4][N][32]
    float* sd1  = (float*)alloc((size_t)N * 2 * 4);
    float* dd1  = (float*)alloc((size_t)N * 2 * 4);
    unsigned short* h1 = (unsigned short*)alloc((size_t)N * 128 * 2);   // bf16 linear [N][128]
    unsigned int* pae0 = (unsigned int*)alloc((size_t)EE * 4);          // src | fp16(alpha h0)
    unsigned int* pae1 = (unsigned int*)alloc((size_t)EE * 4);          // src | fp16(alpha h1)

    unsigned short* xl2 = xl1;               // layer-2 xl (bf16 linear), xl1c dead by then
    float* sd2 = sd1;
    float* dd2 = dd1;

    hipMemsetAsync(bcnt, 0, (size_t)(K + 1) * 4, stream);

    int G   = 256;
    int CH  = (E + G - 1) / G;
    int GB1 = (N + 63) / 64;    // gemm1 blocks (ROWS=64)
    sort_count_kernel<<<G, 256, 0, stream>>>(ei, E, K, CH, bcnt);
    sort_scan_kernel<<<1, MAXK, 0, stream>>>(bcnt, boff, bcur, K, E);
    // fused: scatter (blocks [0,G)) + layer-1 GEMM (blocks [G, G+GB1)) — independent work,
    // bkt and xl1 are distinct buffers so concurrent writes are safe.
    scatter_gemm1_kernel<<<G + GB1, 256, 0, stream>>>(ei, E, K, CH, bcur, bkt,
                                                      x, W1, attS1, attD1, xl1, sd1, dd1, N, G);
    sort_finalize_kernel<<<K, 256, 0, stream>>>(bkt, boff, off, csrc, N);

    // ---- layer 1: alpha precompute, then XCD-affine chunked aggregate ----
    alpha1_kernel<<<(N + 3) / 4, 256, 0, stream>>>(sd1, dd1, off, csrc, pae0, pae1, N);
    int CAB = ((N + 7) / 8) * 8;   // 8-slot groups: chunk = (bid%8)&3, halves via bit 2
    chunk_agg1_kernel<<<CAB, 256, 0, stream>>>(xl1, pae0, pae1, b1, off, h1, N);

    // ---- layer 2 ----
    gemm2_kernel<<<(N + 63) / 64, 256, 0, stream>>>(h1, W2, attS2, attD2, xl2, sd2, dd2, N);
    agg2_kernel<<<(N + 3) / 4, 256, 0, stream>>>(xl2, sd2, dd2, b2, off, csrc, out, N);
}

// Round 5
// 287.112 us; speedup vs baseline: 1.1817x; 1.1817x over previous
//
#include <hip/hip_runtime.h>
#include <cstdint>
#include <cstddef>

#define NEG_SLOPE 0.2f

// Edge packing relies on N <= 65536 (here N = 50000): edge = src | (dst<<16).
// Self-loops are NOT sorted: placed analytically (one per node, first slot).
// csrc[] stores the PACKED edge (src in low 16, dst in high 16).
// NOTE: bkt MUST NOT alias xl1 — scatter and gemm1 run concurrently (fused kernel).
#define NB 128        // nodes per bucket (391 finalize blocks -> fills CUs)
#define LOG_NB 7
#define MAXK 512

__device__ inline unsigned short f2bf(float f) {          // RNE fp32->bf16
    unsigned int u = __float_as_uint(f);
    u += 0x7FFFu + ((u >> 16) & 1u);
    return (unsigned short)(u >> 16);
}
__device__ inline float bf_lo(unsigned int u) { return __uint_as_float(u << 16); }
__device__ inline float bf_hi(unsigned int u) { return __uint_as_float(u & 0xFFFF0000u); }
__device__ inline float bfu(unsigned short u) { return __uint_as_float((unsigned int)u << 16); }

// 8 bf16 MACs from one uint4 of packed bf16
#define FMA8(a, v)                                                                       \
    acc[0] = fmaf(a, bf_lo((v).x), acc[0]); acc[1] = fmaf(a, bf_hi((v).x), acc[1]);      \
    acc[2] = fmaf(a, bf_lo((v).y), acc[2]); acc[3] = fmaf(a, bf_hi((v).y), acc[3]);      \
    acc[4] = fmaf(a, bf_lo((v).z), acc[4]); acc[5] = fmaf(a, bf_hi((v).z), acc[5]);      \
    acc[6] = fmaf(a, bf_lo((v).w), acc[6]); acc[7] = fmaf(a, bf_hi((v).w), acc[7]);

// ---------------- P1: bucket histogram, 4-way wave-replicated (real edges only) ----------------
__global__ __launch_bounds__(256) void sort_count_kernel(const int* __restrict__ ei, int E,
                                                         int K, int CH, int* __restrict__ bcnt) {
    __shared__ int hist[4 * MAXK];
    int tid = threadIdx.x;
    int wiw = tid >> 6;
    for (int i = tid; i < K; i += 256) {
        hist[i] = 0; hist[MAXK + i] = 0; hist[2 * MAXK + i] = 0; hist[3 * MAXK + i] = 0;
    }
    __syncthreads();
    int lo = blockIdx.x * CH;
    int hi = lo + CH; if (hi > E) hi = E;
    for (int e = lo + tid; e < hi; e += 256)
        atomicAdd(&hist[wiw * MAXK + (ei[(size_t)E + e] >> LOG_NB)], 1);
    __syncthreads();
    for (int i = tid; i < K; i += 256) {
        int c = hist[i] + hist[MAXK + i] + hist[2 * MAXK + i] + hist[3 * MAXK + i];
        if (c) atomicAdd(&bcnt[i], c);
    }
}

// ---------------- P2: scan bucket counts ----------------
__global__ void sort_scan_kernel(const int* __restrict__ bcnt, int* __restrict__ boff,
                                 int* __restrict__ bcur, int K, int E) {
    __shared__ int buf[MAXK];
    int tid = threadIdx.x;   // 512 threads
    int v = (tid < K) ? bcnt[tid] : 0;
    buf[tid] = v;
    __syncthreads();
    for (int o = 1; o < MAXK; o <<= 1) {
        int t = (tid >= o) ? buf[tid - o] : 0;
        __syncthreads();
        buf[tid] += t;
        __syncthreads();
    }
    if (tid < K) {
        int ex = buf[tid] - v;
        boff[tid] = ex;
        bcur[tid] = ex;
    }
    if (tid == K) boff[K] = E;
}

// ---- GEMM + fused att dots body: K-tiles of 32 (low LDS, high occupancy) ----
// BF16IN: X is bf16 (packed ushort) instead of fp32 — staging converts to fp32 in LDS.

template <int FOUT, int H, int ROWS, bool BF16IN>
__device__ __forceinline__ void gemm_att_body(const void* __restrict__ Xv,
                                              const float* __restrict__ W,
                                              const float* __restrict__ attS,
                                              const float* __restrict__ attD,
                                              unsigned short* __restrict__ Ybf,
                                              float* __restrict__ as_,
                                              float* __restrict__ ad_, int N, int bid,
                                              float* sX, float* sW) {
    constexpr int CG  = FOUT / 4;
    constexpr int RR  = (ROWS * FOUT) / 1024;   // rows per thread
    constexpr int LDX = 36;                     // 32 + 4 pad
    int tid = threadIdx.x;
    int rowbase = bid * ROWS;
    int cg = tid % CG;
    int rg = tid / CG;
    int r0 = rg * RR;

    float acc[RR][4];
#pragma unroll
    for (int i = 0; i < RR; i++)
#pragma unroll
        for (int c = 0; c < 4; c++) acc[i][c] = 0.f;

    for (int k0 = 0; k0 < 128; k0 += 32) {
        __syncthreads();
        for (int idx = tid; idx < ROWS * 8; idx += 256) {
            int r = idx >> 3, q = idx & 7;
            int row = rowbase + r;
            float4 val;
            if (row < N) {
                if constexpr (BF16IN) {
                    const unsigned short* Xb = (const unsigned short*)Xv;
                    ushort4 raw = *(const ushort4*)&Xb[(size_t)row * 128 + k0 + q * 4];
                    val = make_float4(bfu(raw.x), bfu(raw.y), bfu(raw.z), bfu(raw.w));
                } else {
                    const float* X = (const float*)Xv;
                    val = *(const float4*)&X[(size_t)row * 128 + k0 + q * 4];
                }
            } else {
                val = make_float4(0.f, 0.f, 0.f, 0.f);
            }
            *(float4*)&sX[r * LDX + q * 4] = val;
        }
        for (int idx = tid; idx < 8 * FOUT; idx += 256)
            *(float4*)&sW[idx * 4] = *(const float4*)&W[(size_t)k0 * FOUT + idx * 4];
        __syncthreads();
        for (int k = 0; k < 32; k += 4) {
            float4 xr[RR];
#pragma unroll
            for (int i = 0; i < RR; i++)
                xr[i] = *(const float4*)&sX[(r0 + i) * LDX + k];
#pragma unroll
            for (int kk = 0; kk < 4; kk++) {
                float4 wv = ((const float4*)(sW + (size_t)(k + kk) * FOUT))[cg];
#pragma unroll
                for (int i = 0; i < RR; i++) {
                    float xv = (&xr[i].x)[kk];
                    acc[i][0] = fmaf(xv, wv.x, acc[i][0]);
                    acc[i][1] = fmaf(xv, wv.y, acc[i][1]);
                    acc[i][2] = fmaf(xv, wv.z, acc[i][2]);
                    acc[i][3] = fmaf(xv, wv.w, acc[i][3]);
                }
            }
        }
    }

    // store bf16 Y
#pragma unroll
    for (int i = 0; i < RR; i++) {
        int row = rowbase + r0 + i;
        if (row < N) {
            ushort4 v;
            v.x = f2bf(acc[i][0]); v.y = f2bf(acc[i][1]);
            v.z = f2bf(acc[i][2]); v.w = f2bf(acc[i][3]);
            *(ushort4*)(Ybf + (size_t)row * FOUT + cg * 4) = v;
        }
    }

    // fused att dots
    float4 asv = ((const float4*)attS)[cg];
    float4 adv = ((const float4*)attD)[cg];
    int head = (H == 2) ? (cg >> 4) : 0;
#pragma unroll
    for (int i = 0; i < RR; i++) {
        float ps = acc[i][0] * asv.x + acc[i][1] * asv.y + acc[i][2] * asv.z + acc[i][3] * asv.w;
        float pd = acc[i][0] * adv.x + acc[i][1] * adv.y + acc[i][2] * adv.z + acc[i][3] * adv.w;
#pragma unroll
        for (int o = 1; o <= 8; o <<= 1) { ps += __shfl_xor(ps, o); pd += __shfl_xor(pd, o); }
        int row = rowbase + r0 + i;
        if ((tid & 15) == 0 && row < N) {
            as_[(size_t)row * H + head] = ps;
            ad_[(size_t)row * H + head] = pd;
        }
    }
}

// ---------------- P3 fused with layer-1 GEMM: blocks [0,G) scatter, rest gemm ----------------
__global__ __launch_bounds__(256) void scatter_gemm1_kernel(const int* __restrict__ ei, int E,
                                                            int K, int CH, int* __restrict__ bcur,
                                                            unsigned int* __restrict__ bkt,
                                                            const float* __restrict__ X,
                                                            const float* __restrict__ W1,
                                                            const float* __restrict__ attS,
                                                            const float* __restrict__ attD,
                                                            unsigned short* __restrict__ Ybf,
                                                            float* __restrict__ as_,
                                                            float* __restrict__ ad_, int N, int G) {
    __shared__ float sX[64 * 36];       // 9.2 KB
    __shared__ float sW[32 * 128];      // 16.4 KB
    if (blockIdx.x < G) {
        int* hist = (int*)sX;           // [4][MAXK] = 8 KB <= 9.2 KB
        int* base = (int*)sW;           // MAXK
        int* cur2 = (int*)sW + MAXK;    // MAXK
        int tid = threadIdx.x;
        int wiw = tid >> 6;
        for (int i = tid; i < K; i += 256) {
            hist[i] = 0; hist[MAXK + i] = 0; hist[2 * MAXK + i] = 0; hist[3 * MAXK + i] = 0;
        }
        __syncthreads();
        int lo = blockIdx.x * CH;
        int hi = lo + CH; if (hi > E) hi = E;
        for (int e = lo + tid; e < hi; e += 256)
            atomicAdd(&hist[wiw * MAXK + (ei[(size_t)E + e] >> LOG_NB)], 1);
        __syncthreads();
        for (int i = tid; i < K; i += 256) {
            int c = hist[i] + hist[MAXK + i] + hist[2 * MAXK + i] + hist[3 * MAXK + i];
            base[i] = c ? atomicAdd(&bcur[i], c) : 0;
            cur2[i] = 0;
        }
        __syncthreads();
        for (int e = lo + tid; e < hi; e += 256) {
            int s = ei[e];
            int d = ei[(size_t)E + e];
            int k = d >> LOG_NB;
            int r = atomicAdd(&cur2[k], 1);
            bkt[(size_t)base[k] + r] = (unsigned int)s | ((unsigned int)d << 16);
        }
    } else {
        gemm_att_body<128, 2, 64, false>(X, W1, attS, attD, Ybf, as_, ad_, N, blockIdx.x - G, sX, sW);
    }
}

// ---------------- standalone GEMM (layer 2): FOUT=64, ROWS=64, RR=4, bf16 input (h1) ----------------
__global__ __launch_bounds__(256) void gemm2_kernel(const unsigned short* __restrict__ X,
                                                    const float* __restrict__ W,
                                                    const float* __restrict__ attS,
                                                    const float* __restrict__ attD,
                                                    unsigned short* __restrict__ Ybf,
                                                    float* __restrict__ as_,
                                                    float* __restrict__ ad_, int N) {
    __shared__ float sX[64 * 36];   // 9.2 KB
    __shared__ float sW[32 * 64];   // 8 KB
    gemm_att_body<64, 1, 64, true>(X, W, attS, attD, Ybf, as_, ad_, N, blockIdx.x, sX, sW);
}

// ---------------- P4: per-bucket CSR finalize (replicated hist; +1 self slot per node) ----------------
__global__ __launch_bounds__(256) void sort_finalize_kernel(const unsigned int* __restrict__ bkt,
                                                            const int* __restrict__ boff,
                                                            int* __restrict__ off,
                                                            unsigned int* __restrict__ csrc, int N) {
    __shared__ int nhist[4 * NB];
    __shared__ int part[256];
    __shared__ int loff[NB];
    int k = blockIdx.x;
    int tid = threadIdx.x;
    int wiw = tid >> 6;
    int node0 = k << LOG_NB;
    int nh = N - node0; if (nh > NB) nh = NB;
    int beg = boff[k], end = boff[k + 1];
    for (int i = tid; i < NB; i += 256) {
        nhist[i] = 0; nhist[NB + i] = 0; nhist[2 * NB + i] = 0; nhist[3 * NB + i] = 0;
    }
    __syncthreads();
    for (int e = beg + tid; e < end; e += 256)
        atomicAdd(&nhist[wiw * NB + ((bkt[e] >> 16) - node0)], 1);
    __syncthreads();
    int i0 = 2 * tid, i1 = 2 * tid + 1;
    int v0 = (i0 < nh) ? nhist[i0] + nhist[NB + i0] + nhist[2 * NB + i0] + nhist[3 * NB + i0] + 1 : 0;
    int v1 = (i1 < nh) ? nhist[i1] + nhist[NB + i1] + nhist[2 * NB + i1] + nhist[3 * NB + i1] + 1 : 0;
    part[tid] = v0 + v1;
    __syncthreads();
    for (int o = 1; o < 256; o <<= 1) {
        int t = (tid >= o) ? part[tid - o] : 0;
        __syncthreads();
        part[tid] += t;
        __syncthreads();
    }
    int gbase = beg + node0;   // node0 self slots precede this bucket
    int base = gbase + ((tid > 0) ? part[tid - 1] : 0);
    if (i0 < nh) loff[i0] = base;
    if (i1 < nh) loff[i1] = base + v0;
    __syncthreads();
    for (int i = tid; i < nh; i += 256) {
        int node = node0 + i;
        off[node] = loff[i];
        csrc[loff[i]] = (unsigned int)node | ((unsigned int)node << 16);  // self-loop first
        nhist[i] = loff[i] + 1;    // single-copy cursor
    }
    if (node0 + nh == N && tid == 0) off[N] = gbase + part[255];
    __syncthreads();
    for (int e = beg + tid; e < end; e += 256) {
        unsigned int p = bkt[e];
        int pos = atomicAdd(&nhist[(p >> 16) - node0], 1);
        csrc[pos] = p;   // keep packed (src | dst<<16)
    }
}

// ---------------- layer-1 softmax+aggregate: one wave per NODE, both heads ----------------
// R3 structure with an explicitly software-pipelined consume loop: 4 LDS reads,
// then 4 gathers issued back-to-back (4 misses in flight/wave), then 4 FMA8 blocks.
// Instruction count identical to R3 — pure reorder to raise miss concurrency.

__global__ __launch_bounds__(256) void agg1_kernel(const unsigned short* __restrict__ xl,
                                                   const float* __restrict__ as_,
                                                   const float* __restrict__ ad_,
                                                   const float* __restrict__ bias,
                                                   const int* __restrict__ off,
                                                   const unsigned int* __restrict__ csrc,
                                                   unsigned short* __restrict__ out, int N) {
    __shared__ float4 sps[4][64];   // {p0, p1, as_int(byteoff), -}
    int wiw  = threadIdx.x >> 6;
    int lane = threadIdx.x & 63;
    int node = blockIdx.x * 4 + wiw;
    if (node >= N) return;
    int beg = off[node], end = off[node + 1];
    int deg = end - beg;
    float2 adn = ((const float2*)ad_)[node];

    int cl  = lane & 15;
    int sub = lane >> 4;
    int hd1 = (cl >> 3) & 1;
    float acc[8];
#pragma unroll
    for (int i = 0; i < 8; i++) acc[i] = 0.f;
    const char* xbase = (const char*)xl + cl * 16;   // + src*256

    if (deg <= 64) {
        int so = 0;
        float t0 = -1e30f, t1 = -1e30f;
        if (lane < deg) {
            int s = (int)(csrc[beg + lane] & 0xFFFFu);
            so = s << 8;                       // byte offset of row
            float2 asv = ((const float2*)as_)[s];
            t0 = asv.x + adn.x; t0 = t0 > 0.f ? t0 : NEG_SLOPE * t0;
            t1 = asv.y + adn.y; t1 = t1 > 0.f ? t1 : NEG_SLOPE * t1;
        }
        float m0 = t0, m1 = t1;
#pragma unroll
        for (int o = 32; o; o >>= 1) {
            m0 = fmaxf(m0, __shfl_xor(m0, o));
            m1 = fmaxf(m1, __shfl_xor(m1, o));
        }
        float e0 = (lane < deg) ? __expf(t0 - m0) : 0.f;
        float e1 = (lane < deg) ? __expf(t1 - m1) : 0.f;
        float s0 = e0, s1 = e1;
#pragma unroll
        for (int o = 32; o; o >>= 1) { s0 += __shfl_xor(s0, o); s1 += __shfl_xor(s1, o); }
        sps[wiw][lane] = make_float4(e0 / s0, e1 / s1, __int_as_float(so), 0.f);
        int iters = (deg + 3) >> 2;   // <= 16
        int g = 0;
        for (; g + 4 <= iters; g += 4) {     // pipelined: 4 gathers in flight
            float4 q0 = sps[wiw][(g + 0) * 4 + sub];
            float4 q1 = sps[wiw][(g + 1) * 4 + sub];
            float4 q2 = sps[wiw][(g + 2) * 4 + sub];
            float4 q3 = sps[wiw][(g + 3) * 4 + sub];
            uint4 v0 = *(const uint4*)(xbase + __float_as_int(q0.z));
            uint4 v1 = *(const uint4*)(xbase + __float_as_int(q1.z));
            uint4 v2 = *(const uint4*)(xbase + __float_as_int(q2.z));
            uint4 v3 = *(const uint4*)(xbase + __float_as_int(q3.z));
            float a0 = hd1 ? q0.y : q0.x;
            float a1 = hd1 ? q1.y : q1.x;
            float a2 = hd1 ? q2.y : q2.x;
            float a3 = hd1 ? q3.y : q3.x;
            FMA8(a0, v0) FMA8(a1, v1) FMA8(a2, v2) FMA8(a3, v3)
        }
        for (; g < iters; g++) {             // tail (<=3)
            float4 q = sps[wiw][g * 4 + sub];
            uint4 v  = *(const uint4*)(xbase + __float_as_int(q.z));
            float a  = hd1 ? q.y : q.x;
            FMA8(a, v)
        }
    } else {
        // 3-pass fallback (deg > 64) — statistically dead for this graph
        float m0 = -1e30f, m1 = -1e30f;
        for (int b = beg; b < end; b += 64) {
            int e = b + lane;
            if (e < end) {
                int s = (int)(csrc[e] & 0xFFFFu);
                float2 asv = ((const float2*)as_)[s];
                float t0 = asv.x + adn.x; t0 = t0 > 0.f ? t0 : NEG_SLOPE * t0;
                float t1 = asv.y + adn.y; t1 = t1 > 0.f ? t1 : NEG_SLOPE * t1;
                m0 = fmaxf(m0, t0); m1 = fmaxf(m1, t1);
            }
        }
#pragma unroll
        for (int o = 32; o; o >>= 1) {
            m0 = fmaxf(m0, __shfl_xor(m0, o));
            m1 = fmaxf(m1, __shfl_xor(m1, o));
        }
        float s0 = 0.f, s1 = 0.f;
        for (int b = beg; b < end; b += 64) {
            int e = b + lane;
            if (e < end) {
                int s = (int)(csrc[e] & 0xFFFFu);
                float2 asv = ((const float2*)as_)[s];
                float t0 = asv.x + adn.x; t0 = t0 > 0.f ? t0 : NEG_SLOPE * t0;
                float t1 = asv.y + adn.y; t1 = t1 > 0.f ? t1 : NEG_SLOPE * t1;
                s0 += __expf(t0 - m0); s1 += __expf(t1 - m1);
            }
        }
#pragma unroll
        for (int o = 32; o; o >>= 1) { s0 += __shfl_xor(s0, o); s1 += __shfl_xor(s1, o); }
        float i0 = 1.f / s0, i1 = 1.f / s1;
        for (int b = beg; b < end; b += 64) {
            int cnt = end - b; if (cnt > 64) cnt = 64;
            float p0 = 0.f, p1 = 0.f; int so = 0;
            if (lane < cnt) {
                int s = (int)(csrc[b + lane] & 0xFFFFu);
                so = s << 8;
                float2 asv = ((const float2*)as_)[s];
                float t0 = asv.x + adn.x; t0 = t0 > 0.f ? t0 : NEG_SLOPE * t0;
                float t1 = asv.y + adn.y; t1 = t1 > 0.f ? t1 : NEG_SLOPE * t1;
                p0 = __expf(t0 - m0) * i0; p1 = __expf(t1 - m1) * i1;
            }
            sps[wiw][lane] = make_float4(p0, p1, __int_as_float(so), 0.f);
            int iters = (cnt + 3) >> 2;
#pragma unroll 8
            for (int j = 0; j < iters; j++) {
                float4 q = sps[wiw][j * 4 + sub];
                float a  = hd1 ? q.y : q.x;
                uint4 v  = *(const uint4*)(xbase + __float_as_int(q.z));
                FMA8(a, v)
            }
        }
    }
#pragma unroll
    for (int o = 16; o <= 32; o <<= 1)
#pragma unroll
        for (int i = 0; i < 8; i++) acc[i] += __shfl_xor(acc[i], o);
    if (sub == 0) {
        const float* bp = bias + cl * 8;
        // relu(acc+bias) -> bf16, packed: one 16B store instead of eight dword stores
        unsigned int w0 = (unsigned int)f2bf(fmaxf(acc[0] + bp[0], 0.f)) |
                          ((unsigned int)f2bf(fmaxf(acc[1] + bp[1], 0.f)) << 16);
        unsigned int w1 = (unsigned int)f2bf(fmaxf(acc[2] + bp[2], 0.f)) |
                          ((unsigned int)f2bf(fmaxf(acc[3] + bp[3], 0.f)) << 16);
        unsigned int w2 = (unsigned int)f2bf(fmaxf(acc[4] + bp[4], 0.f)) |
                          ((unsigned int)f2bf(fmaxf(acc[5] + bp[5], 0.f)) << 16);
        unsigned int w3 = (unsigned int)f2bf(fmaxf(acc[6] + bp[6], 0.f)) |
                          ((unsigned int)f2bf(fmaxf(acc[7] + bp[7], 0.f)) << 16);
        uint4 pack = make_uint4(w0, w1, w2, w3);
        *(uint4*)(out + (size_t)node * 128 + cl * 8) = pack;
    }
}

// ---------------- layer-2 softmax+aggregate: one wave per node, H=1, fp32 out ----------------
// Same pipelined consume loop (4 gathers in flight).

__global__ __launch_bounds__(256) void agg2_kernel(const unsigned short* __restrict__ xl,
                                                   const float* __restrict__ as_,
                                                   const float* __restrict__ ad_,
                                                   const float* __restrict__ bias,
                                                   const int* __restrict__ off,
                                                   const unsigned int* __restrict__ csrc,
                                                   float* __restrict__ out, int N) {
    __shared__ float2 sps[4][64];   // {p, as_int(byteoff)}
    int wiw  = threadIdx.x >> 6;
    int lane = threadIdx.x & 63;
    int node = blockIdx.x * 4 + wiw;
    if (node >= N) return;
    int beg = off[node], end = off[node + 1];
    int deg = end - beg;
    float adn = ad_[node];

    int cl  = lane & 7;
    int sub = lane >> 3;
    float acc[8];
#pragma unroll
    for (int i = 0; i < 8; i++) acc[i] = 0.f;
    const char* xbase = (const char*)xl + cl * 16;   // + src*128

    if (deg <= 64) {
        int so = 0;
        float t = -1e30f;
        if (lane < deg) {
            int s = (int)(csrc[beg + lane] & 0xFFFFu);
            so = s << 7;
            t = as_[s] + adn;
            t = t > 0.f ? t : NEG_SLOPE * t;
        }
        float m = t;
#pragma unroll
        for (int o = 32; o; o >>= 1) m = fmaxf(m, __shfl_xor(m, o));
        float evv = (lane < deg) ? __expf(t - m) : 0.f;
        float sum = evv;
#pragma unroll
        for (int o = 32; o; o >>= 1) sum += __shfl_xor(sum, o);
        sps[wiw][lane] = make_float2(evv / sum, __int_as_float(so));
        int iters = (deg + 7) >> 3;   // <= 8
        int g = 0;
        for (; g + 4 <= iters; g += 4) {     // pipelined: 4 gathers in flight
            float2 q0 = sps[wiw][(g + 0) * 8 + sub];
            float2 q1 = sps[wiw][(g + 1) * 8 + sub];
            float2 q2 = sps[wiw][(g + 2) * 8 + sub];
            float2 q3 = sps[wiw][(g + 3) * 8 + sub];
            uint4 v0 = *(const uint4*)(xbase + __float_as_int(q0.y));
            uint4 v1 = *(const uint4*)(xbase + __float_as_int(q1.y));
            uint4 v2 = *(const uint4*)(xbase + __float_as_int(q2.y));
            uint4 v3 = *(const uint4*)(xbase + __float_as_int(q3.y));
            FMA8(q0.x, v0) FMA8(q1.x, v1) FMA8(q2.x, v2) FMA8(q3.x, v3)
        }
        for (; g < iters; g++) {             // tail (<=3)
            float2 q = sps[wiw][g * 8 + sub];
            uint4 v  = *(const uint4*)(xbase + __float_as_int(q.y));
            FMA8(q.x, v)
        }
    } else {
        float m = -1e30f;
        for (int b = beg; b < end; b += 64) {
            int e = b + lane;
            if (e < end) {
                float t = as_[csrc[e] & 0xFFFFu] + adn;
                t = t > 0.f ? t : NEG_SLOPE * t;
                m = fmaxf(m, t);
            }
        }
#pragma unroll
        for (int o = 32; o; o >>= 1) m = fmaxf(m, __shfl_xor(m, o));
        float sum = 0.f;
        for (int b = beg; b < end; b += 64) {
            int e = b + lane;
            if (e < end) {
                float t = as_[csrc[e] & 0xFFFFu] + adn;
                t = t > 0.f ? t : NEG_SLOPE * t;
                sum += __expf(t - m);
            }
        }
#pragma unroll
        for (int o = 32; o; o >>= 1) sum += __shfl_xor(sum, o);
        float inv = 1.f / sum;
        for (int b = beg; b < end; b += 64) {
            int cnt = end - b; if (cnt > 64) cnt = 64;
            float p = 0.f; int so = 0;
            if (lane < cnt) {
                int s = (int)(csrc[b + lane] & 0xFFFFu);
                so = s << 7;
                float t = as_[s] + adn;
                t = t > 0.f ? t : NEG_SLOPE * t;
                p = __expf(t - m) * inv;
            }
            sps[wiw][lane] = make_float2(p, __int_as_float(so));
            int iters = (cnt + 7) >> 3;
#pragma unroll 8
            for (int j = 0; j < iters; j++) {
                float2 q = sps[wiw][j * 8 + sub];
                float a  = q.x;
                uint4 v  = *(const uint4*)(xbase + __float_as_int(q.y));
                FMA8(a, v)
            }
        }
    }
#pragma unroll
    for (int o = 8; o <= 32; o <<= 1)
#pragma unroll
        for (int i = 0; i < 8; i++) acc[i] += __shfl_xor(acc[i], o);
    if (sub == 0) {
        float* op = out + (size_t)node * 64 + cl * 8;
        const float* bp = bias + cl * 8;
#pragma unroll
        for (int i = 0; i < 8; i++) op[i] = fmaxf(acc[i] + bp[i], 0.f);
    }
}

// ---------------- launcher ----------------

extern "C" void kernel_launch(void* const* d_in, const int* in_sizes, int n_in,
                              void* d_out, int out_size, void* d_ws, size_t ws_size,
                              hipStream_t stream) {
    const float* x        = (const float*)d_in[0];
    const int*   ei       = (const int*)d_in[1];   // int32 per harness convention
    const float* W1       = (const float*)d_in[2];
    const float* attS1    = (const float*)d_in[3];
    const float* attD1    = (const float*)d_in[4];
    const float* b1       = (const float*)d_in[5];
    const float* W2       = (const float*)d_in[6];
    const float* attS2    = (const float*)d_in[7];
    const float* attD2    = (const float*)d_in[8];
    const float* b2       = (const float*)d_in[9];
    float* out            = (float*)d_out;

    int N  = in_sizes[0] / 128;
    int E  = in_sizes[1] / 2;
    int EE = E + N;                    // with self-loops
    int K  = (N + NB - 1) >> LOG_NB;   // buckets (391 for N=50000)

    char* w = (char*)d_ws;
    auto alloc = [&](size_t bytes) -> void* {
        void* p = (void*)w;
        w += (bytes + 255) & ~(size_t)255;
        return p;
    };
    int*   bcnt = (int*)alloc((size_t)(K + 1) * 4);
    int*   boff = (int*)alloc((size_t)(K + 1) * 4);
    int*   bcur = (int*)alloc((size_t)(K + 1) * 4);
    int*   off  = (int*)alloc((size_t)(N + 1) * 4);
    unsigned int* csrc = (unsigned int*)alloc((size_t)EE * 4);
    unsigned int* bkt  = (unsigned int*)alloc((size_t)E * 4);           // OWN buffer (no alias!)
    unsigned short* xl1 = (unsigned short*)alloc((size_t)N * 128 * 2);  // bf16 linear; reused as xl2
    float* sd1  = (float*)alloc((size_t)N * 2 * 4);
    float* dd1  = (float*)alloc((size_t)N * 2 * 4);
    unsigned short* h1 = (unsigned short*)alloc((size_t)N * 128 * 2);   // bf16

    unsigned short* xl2 = xl1;               // layer-2 xl (bf16), xl1 dead by then
    float* sd2 = sd1;
    float* dd2 = dd1;

    hipMemsetAsync(bcnt, 0, (size_t)(K + 1) * 4, stream);

    int G   = 256;
    int CH  = (E + G - 1) / G;
    int GB1 = (N + 63) / 64;    // gemm1 blocks (ROWS=64)
    sort_count_kernel<<<G, 256, 0, stream>>>(ei, E, K, CH, bcnt);
    sort_scan_kernel<<<1, MAXK, 0, stream>>>(bcnt, boff, bcur, K, E);
    // fused: scatter (blocks [0,G)) + layer-1 GEMM (blocks [G, G+GB1)) — independent work,
    // bkt and xl1 are distinct buffers so concurrent writes are safe.
    scatter_gemm1_kernel<<<G + GB1, 256, 0, stream>>>(ei, E, K, CH, bcur, bkt,
                                                      x, W1, attS1, attD1, xl1, sd1, dd1, N, G);
    sort_finalize_kernel<<<K, 256, 0, stream>>>(bkt, boff, off, csrc, N);

    // ---- layer 1 aggregate (1 node/wave) ----
    agg1_kernel<<<(N + 3) / 4, 256, 0, stream>>>(xl1, sd1, dd1, b1, off, csrc, h1, N);

    // ---- layer 2 ----
    gemm2_kernel<<<(N + 63) / 64, 256, 0, stream>>>(h1, W2, attS2, attD2, xl2, sd2, dd2, N);
    agg2_kernel<<<(N + 3) / 4, 256, 0, stream>>>(xl2, sd2, dd2, b2, off, csrc, out, N);
}